// Round 8
// baseline (7035.563 us; speedup 1.0000x reference)
//
#include <hip/hip_runtime.h>
#include <hip/hip_fp16.h>

// Bidirectional GRU, b=32, t=2048, in=hid=256, gate order r,z,n.
// gx = x@W_ih^T + b_ih (+b_hr,b_hz) precomputed fp16 in d_ws.
// R8: hybrid at 12 waves: VALU role 2 waves/SIMD (TLP hides LDS stalls --
// R6's miss), MFMA role 1 wave/SIMD (12 indep chains tolerate latency),
// total wave count kept low (R7's 16-wave barriers cost ~2000 cyc/step).
// Rates (measured): dot2 4.5 cyc/SIMD, mfma_16x16x32 ~19 cyc/SIMD.
// VALU waves 0-7: rows 384-767 (865 cyc) || MFMA waves 8-11: rows 0-383
// (930 cyc). Gate on waves 0-3; gx prefetch on waves 8-9.

typedef __fp16 half2_t __attribute__((ext_vector_type(2)));
typedef __fp16 half8_t __attribute__((ext_vector_type(8)));
typedef float  f32x4   __attribute__((ext_vector_type(4)));

static constexpr int T_STEPS = 2048;
static constexpr int BATCH   = 32;
static constexpr int HID     = 256;
static constexpr int IN      = 256;
static constexpr int G3      = 768;   // 3*HID

__device__ __forceinline__ float fdot2(half2_t a, half2_t b, float c) {
    return __builtin_amdgcn_fdot2(a, b, c, false);
}

// LDS-order-only barrier: leaves global-load/store acks (vmcnt) in flight.
__device__ __forceinline__ void barrier_lgkm() {
    asm volatile("s_waitcnt lgkmcnt(0)\n\ts_barrier" ::: "memory");
}

// ---------------------------------------------------------------------------
// Kernel 1: gx[m][j] = sum_k x[m][k]*W_ih[j][k] + b_ih[j] (+ b_hh[j] for the
// r,z thirds). Stored fp16.
// ---------------------------------------------------------------------------
__global__ __launch_bounds__(256, 2) void gx_gemm(
        const float* __restrict__ x,
        const float* __restrict__ Wih,
        const float* __restrict__ bih,
        const float* __restrict__ bhh,
        _Float16* __restrict__ gx) {
    __shared__ ushort As[64 * 256];   // 32KB
    __shared__ ushort Bs[64 * 256];   // 32KB

    const int tid = threadIdx.x;
    const int m0  = blockIdx.x * 64;
    const int tx  = tid & 15;         // n-dim
    const int ty  = tid >> 4;         // m-dim

#pragma unroll
    for (int i = 0; i < 16; ++i) {
        int f    = tid + 256 * i;
        int row  = f >> 6;
        int col4 = f & 63;
        float4 v = *(const float4*)(x + (size_t)(m0 + row) * IN + col4 * 4);
        half2_t h0 = __builtin_amdgcn_cvt_pkrtz(v.x, v.y);
        half2_t h1 = __builtin_amdgcn_cvt_pkrtz(v.z, v.w);
        int chunk = col4 >> 1;
        int idx = row * 256 + ((chunk ^ (row & 7)) * 8) + (col4 & 1) * 4;
        uint2 wv;
        wv.x = __builtin_bit_cast(unsigned, h0);
        wv.y = __builtin_bit_cast(unsigned, h1);
        *(uint2*)(As + idx) = wv;
    }

    for (int nb = 0; nb < 12; ++nb) {
#pragma unroll
        for (int i = 0; i < 16; ++i) {
            int f    = tid + 256 * i;
            int row  = f >> 6;
            int col4 = f & 63;
            float4 v = *(const float4*)(Wih + (size_t)(nb * 64 + row) * IN + col4 * 4);
            half2_t h0 = __builtin_amdgcn_cvt_pkrtz(v.x, v.y);
            half2_t h1 = __builtin_amdgcn_cvt_pkrtz(v.z, v.w);
            int chunk = col4 >> 1;
            int idx = row * 256 + ((chunk ^ (row & 7)) * 8) + (col4 & 1) * 4;
            uint2 wv;
            wv.x = __builtin_bit_cast(unsigned, h0);
            wv.y = __builtin_bit_cast(unsigned, h1);
            *(uint2*)(Bs + idx) = wv;
        }
        barrier_lgkm();

        float acc[4][4];
#pragma unroll
        for (int jm = 0; jm < 4; ++jm)
#pragma unroll
            for (int jn = 0; jn < 4; ++jn) acc[jm][jn] = 0.f;

#pragma unroll 4
        for (int kc = 0; kc < 32; ++kc) {
            union { uint4 u; half2_t h[4]; } av[4], bv[4];
#pragma unroll
            for (int jm = 0; jm < 4; ++jm) {
                int r = ty * 4 + jm;
                av[jm].u = *(const uint4*)(As + r * 256 + ((kc ^ (r & 7)) * 8));
            }
#pragma unroll
            for (int jn = 0; jn < 4; ++jn) {
                int r = tx + 16 * jn;
                bv[jn].u = *(const uint4*)(Bs + r * 256 + ((kc ^ (r & 7)) * 8));
            }
#pragma unroll
            for (int jm = 0; jm < 4; ++jm)
#pragma unroll
                for (int jn = 0; jn < 4; ++jn)
#pragma unroll
                    for (int p = 0; p < 4; ++p)
                        acc[jm][jn] = fdot2(av[jm].h[p], bv[jn].h[p], acc[jm][jn]);
        }

#pragma unroll
        for (int jn = 0; jn < 4; ++jn) {
            int n = nb * 64 + tx + 16 * jn;
            float bias = bih[n] + (n < 512 ? bhh[n] : 0.f);
#pragma unroll
            for (int jm = 0; jm < 4; ++jm) {
                int m = m0 + ty * 4 + jm;
                gx[(size_t)m * G3 + n] = (_Float16)(acc[jm][jn] + bias);
            }
        }
        barrier_lgkm();   // WAR: Bs restage next iteration
    }
}

// ---------------------------------------------------------------------------
// Kernel 2: hybrid recurrence. grid=64 (b,dir), block=768 (12 waves).
//   VALU waves 0-7 (2/SIMD): rows 384..767. Wave w: kseg s=w&3 (64 k),
//     rowgrp g=w>>2; lane: 3 rows x 64 k = 96 dot2 -> PV[s][row-384].
//   MFMA waves 8-11 (1/SIMD): rows 0..383; wave mw: 6 tiles x 8 K-chain
//     (12 independent depth-4 chains) -> ghM. Waves 8-9 prefetch gx.
//   Gate: waves 0-3 (tid<256). 2 lgkm-only barriers/step.
// ---------------------------------------------------------------------------
__global__ __launch_bounds__(768) void gru_seq(
        const _Float16* __restrict__ gx,
        const float* __restrict__ Whh,
        const float* __restrict__ bhh,
        float* __restrict__ out0,     // outputs [32,2048,512]
        float* __restrict__ out1) {   // hiddens [2048,32,512]
    __shared__ float  ghM[384];       // MFMA results, rows 0..383
    __shared__ float  PV[4][384];     // VALU partials by kseg, rows 384..767
    __shared__ ushort h16[256];       // h as fp16
    __shared__ ushort gxb[768];       // this step's gx row (fp16)

    const int tid = threadIdx.x;
    const int b   = blockIdx.x & 31;
    const int d   = blockIdx.x >> 5;
    const int w   = tid >> 6;
    const int L   = tid & 63;

    const int tp0 = d ? (T_STEPS - 1) : 0;
    const int sgn = d ? -1 : 1;

    if (tid < 256) h16[tid] = 0;      // h0 = 0
    __syncthreads();

    if (w < 8) {
        // ================= VALU + gate waves (2 per SIMD) =================
        const int s  = w & 3;             // k segment (64 k's)
        const int g  = w >> 2;            // row group (0..1)
        const int r0 = g * 192 + 3 * L;   // row offset from 384

        // weights: 3 rows x 32 half2, k = s*64 + 2q
        half2_t Wv[3][32];
#pragma unroll
        for (int j = 0; j < 3; ++j) {
            const float* wr_ = Whh + (size_t)(384 + r0 + j) * HID + s * 64;
#pragma unroll
            for (int q = 0; q < 32; ++q) {
                float2 f = *(const float2*)(wr_ + 2 * q);
                Wv[j][q] = __builtin_amdgcn_cvt_pkrtz(f.x, f.y);
            }
        }

        float bh_n = 0.f, hprev = 0.f;
        float* o0 = out0;
        float* o1 = out1;
        if (tid < 256) {
            bh_n = bhh[512 + tid];
            o0 = out0 + ((size_t)b * T_STEPS + tp0) * 512 + d * 256 + tid;
            o1 = out1 + ((size_t)tp0 * BATCH + b) * 512 + d * 256 + tid;
        }
        const int o0d = sgn * 512;
        const int o1d = sgn * (BATCH * 512);

        const ushort* hq = h16 + s * 64;
        const _Float16* gxh = (const _Float16*)gxb;

        for (int t = 0; t < T_STEPS; ++t) {
            // hoist all h reads: one latency exposure, hidden by 2-wave TLP
            union { uint4 u; half2_t h[4]; } hv[8];
#pragma unroll
            for (int c = 0; c < 8; ++c)
                hv[c].u = *(const uint4*)(hq + c * 8);    // broadcast reads

            // ---- dot phase: 96 dot2 (3 rows x 64 k) ----
            float a0 = 0.f, a1 = 0.f, a2 = 0.f;
#pragma unroll
            for (int c = 0; c < 8; ++c)
#pragma unroll
                for (int p = 0; p < 4; ++p) {
                    const int q = c * 4 + p;
                    a0 = fdot2(Wv[0][q], hv[c].h[p], a0);
                    a1 = fdot2(Wv[1][q], hv[c].h[p], a1);
                    a2 = fdot2(Wv[2][q], hv[c].h[p], a2);
                }
            PV[s][r0 + 0] = a0;
            PV[s][r0 + 1] = a1;
            PV[s][r0 + 2] = a2;

            barrier_lgkm();

            // ---- gate phase (waves 0-3) ----
            if (tid < 256) {
                const int i = tid;
                float hr = ghM[i];
                float hz = (i < 128) ? ghM[256 + i]
                                     : ((PV[0][i - 128] + PV[1][i - 128])
                                      + (PV[2][i - 128] + PV[3][i - 128]));
                float hn = (PV[0][128 + i] + PV[1][128 + i])
                         + (PV[2][128 + i] + PV[3][128 + i]);
                float xr = (float)gxh[i]       + hr;   // biases folded in gx
                float xz = (float)gxh[256 + i] + hz;
                float r = __builtin_amdgcn_rcpf(1.f + __builtin_amdgcn_exp2f(xr * -1.44269504f));
                float z = __builtin_amdgcn_rcpf(1.f + __builtin_amdgcn_exp2f(xz * -1.44269504f));
                float nx = (float)gxh[512 + i] + r * (hn + bh_n);
                float e2 = __builtin_amdgcn_exp2f(nx * 2.88539008f);
                float n  = 1.f - 2.f * __builtin_amdgcn_rcpf(1.f + e2);   // tanh
                float h  = n + z * (hprev - n);
                hprev = h;

                h16[i] = __builtin_bit_cast(ushort, (_Float16)h);
                *o0 = h; *o1 = h;
                o0 += o0d; o1 += o1d;
            }
            barrier_lgkm();
        }
    } else {
        // ================= MFMA waves (1 per SIMD) =================
        const int mw = w - 8;             // 0..3: rows 96*mw .. 96*mw+95
        // A-fragments: 6 tiles x 8 K-slices. lane: row=(L&15), k=(L>>4)*8+e
        half8_t Wn[6][8];
        {
            const int mrow = L & 15;
            const int klo  = (L >> 4) * 8;
#pragma unroll
            for (int nt = 0; nt < 6; ++nt)
#pragma unroll
                for (int kh = 0; kh < 8; ++kh) {
                    const float* p = Whh + (size_t)(96 * mw + nt * 16 + mrow) * HID
                                   + kh * 32 + klo;
                    union { half8_t v; half2_t h[4]; } u;
#pragma unroll
                    for (int q = 0; q < 4; ++q) {
                        float2 f = *(const float2*)(p + 2 * q);
                        u.h[q] = __builtin_amdgcn_cvt_pkrtz(f.x, f.y);
                    }
                    Wn[nt][kh] = u.v;
                }
        }

        // gx prefetch on waves 8-9 (threads 512..607)
        const int pt = tid - 512;
        const bool pf = (unsigned)pt < 96u;
        const _Float16* gp = gx + ((size_t)b * T_STEPS + tp0) * G3 + (pf ? pt * 8 : 0);
        const int gpd = sgn * G3;
        uint4 greg{};
        if (pf) greg = *(const uint4*)gp;

        const ushort* hseg = h16 + (L >> 4) * 8;
        float* pw0 = ghM + (L >> 4) * 4;
        const bool wr = (L & 15) == 0;
        const f32x4 zz = {0.f, 0.f, 0.f, 0.f};   // hoisted acc-init

        for (int t = 0; t < T_STEPS; ++t) {
            // land step-t gx row; issue step-t+1 load (stays in flight
            // across the lgkm-only barriers)
            if (pf) {
                *(uint4*)(gxb + pt * 8) = greg;
                if (t + 1 < T_STEPS) {
                    gp += gpd;
                    greg = *(const uint4*)gp;
                }
            }

            // ---- B fragments: h, broadcast across the 16 columns ----
            union { uint4 u; half8_t v; } bf[8];
#pragma unroll
            for (int kh = 0; kh < 8; ++kh)
                bf[kh].u = *(const uint4*)(hseg + kh * 32);

            // ---- 6 tiles x (2 independent depth-4 chains) ----
#pragma unroll
            for (int nt = 0; nt < 6; ++nt) {
                f32x4 accA = __builtin_amdgcn_mfma_f32_16x16x32_f16(Wn[nt][0], bf[0].v, zz, 0, 0, 0);
                f32x4 accB = __builtin_amdgcn_mfma_f32_16x16x32_f16(Wn[nt][4], bf[4].v, zz, 0, 0, 0);
                accA = __builtin_amdgcn_mfma_f32_16x16x32_f16(Wn[nt][1], bf[1].v, accA, 0, 0, 0);
                accB = __builtin_amdgcn_mfma_f32_16x16x32_f16(Wn[nt][5], bf[5].v, accB, 0, 0, 0);
                accA = __builtin_amdgcn_mfma_f32_16x16x32_f16(Wn[nt][2], bf[2].v, accA, 0, 0, 0);
                accB = __builtin_amdgcn_mfma_f32_16x16x32_f16(Wn[nt][6], bf[6].v, accB, 0, 0, 0);
                accA = __builtin_amdgcn_mfma_f32_16x16x32_f16(Wn[nt][3], bf[3].v, accA, 0, 0, 0);
                accB = __builtin_amdgcn_mfma_f32_16x16x32_f16(Wn[nt][7], bf[7].v, accB, 0, 0, 0);
                if (wr) {
                    f32x4 sm = accA + accB;
                    *(f32x4*)(pw0 + (6 * mw + nt) * 16) = sm;
                }
            }

            barrier_lgkm();   // partials published; gate runs on waves 0-3
            barrier_lgkm();   // h16 updated; safe to read next step
        }
    }
}

// ---------------------------------------------------------------------------
extern "C" void kernel_launch(void* const* d_in, const int* in_sizes, int n_in,
                              void* d_out, int out_size, void* d_ws, size_t ws_size,
                              hipStream_t stream) {
    const float* x   = (const float*)d_in[0];
    const float* Wih = (const float*)d_in[1];
    const float* Whh = (const float*)d_in[2];
    const float* bih = (const float*)d_in[3];
    const float* bhh = (const float*)d_in[4];

    float* out0 = (float*)d_out;                          // outputs [32,2048,512]
    float* out1 = out0 + (size_t)BATCH * T_STEPS * 512;   // hiddens [2048,32,512]

    _Float16* gx = (_Float16*)d_ws;                       // 96MB

    gx_gemm<<<dim3(65536 / 64), dim3(256), 0, stream>>>(x, Wih, bih, bhh, gx);
    gru_seq<<<dim3(BATCH * 2), dim3(768), 0, stream>>>(gx, Whh, bhh, out0, out1);
}

// Round 10
// 2558.382 us; speedup vs baseline: 2.7500x; 2.7500x over previous
//
#include <hip/hip_runtime.h>
#include <hip/hip_fp16.h>

// Bidirectional GRU, b=32, t=2048, in=hid=256, gate order r,z,n.
// gx = x@W_ih^T + b_ih (+b_hr,b_hz folded) precomputed fp16 in d_ws.
// Recurrence: 64 WGs (batch x dir), 768 threads = 12 waves = 4 k-seg x 3
// row-groups, 128 packed-fp16 W regs per lane, v_dot2 inner loop.
// R10: fixes R9's double-counted b_hr/b_hz (gx_gemm folds them into gx;
// gru_seq must fold ONLY b_hn, rows 512..767, into the dot partials).
// Keeps R9's amdgpu_waves_per_eu(1,3): min=1 -> 512-reg/wave budget so
// the 128 W regs can live in ARCH VGPRs (testing the AGPR-copy-tax
// theory); max=3 truthful (3 waves x 512 <= 2048 SIMD pool).

typedef __fp16 half2_t __attribute__((ext_vector_type(2)));

static constexpr int T_STEPS = 2048;
static constexpr int BATCH   = 32;
static constexpr int HID     = 256;
static constexpr int IN      = 256;
static constexpr int G3      = 768;   // 3*HID

__device__ __forceinline__ float fdot2(half2_t a, half2_t b, float c) {
    return __builtin_amdgcn_fdot2(a, b, c, false);
}

// __syncthreads() drains vmcnt(0) (store acks + prefetch) -- we only need
// LDS ordering, so wait lgkmcnt(0) and barrier.
__device__ __forceinline__ void barrier_lgkm() {
    asm volatile("s_waitcnt lgkmcnt(0)\n\ts_barrier" ::: "memory");
}

// ---------------------------------------------------------------------------
// Kernel 1: gx[m][j] = sum_k x[m][k]*W_ih[j][k] + b_ih[j] (+ b_hh[j] for the
// r,z thirds). Stored fp16.
// ---------------------------------------------------------------------------
__global__ __launch_bounds__(256, 2) void gx_gemm(
        const float* __restrict__ x,
        const float* __restrict__ Wih,
        const float* __restrict__ bih,
        const float* __restrict__ bhh,
        _Float16* __restrict__ gx) {
    __shared__ ushort As[64 * 256];   // 32KB
    __shared__ ushort Bs[64 * 256];   // 32KB

    const int tid = threadIdx.x;
    const int m0  = blockIdx.x * 64;
    const int tx  = tid & 15;         // n-dim
    const int ty  = tid >> 4;         // m-dim

    // ---- stage A tile (x): 64 rows x 256 cols ----
#pragma unroll
    for (int i = 0; i < 16; ++i) {
        int f    = tid + 256 * i;
        int row  = f >> 6;
        int col4 = f & 63;
        float4 v = *(const float4*)(x + (size_t)(m0 + row) * IN + col4 * 4);
        half2_t h0 = __builtin_amdgcn_cvt_pkrtz(v.x, v.y);
        half2_t h1 = __builtin_amdgcn_cvt_pkrtz(v.z, v.w);
        int chunk = col4 >> 1;
        int idx = row * 256 + ((chunk ^ (row & 7)) * 8) + (col4 & 1) * 4;
        uint2 wv;
        wv.x = __builtin_bit_cast(unsigned, h0);
        wv.y = __builtin_bit_cast(unsigned, h1);
        *(uint2*)(As + idx) = wv;
    }

    for (int nb = 0; nb < 12; ++nb) {
#pragma unroll
        for (int i = 0; i < 16; ++i) {
            int f    = tid + 256 * i;
            int row  = f >> 6;
            int col4 = f & 63;
            float4 v = *(const float4*)(Wih + (size_t)(nb * 64 + row) * IN + col4 * 4);
            half2_t h0 = __builtin_amdgcn_cvt_pkrtz(v.x, v.y);
            half2_t h1 = __builtin_amdgcn_cvt_pkrtz(v.z, v.w);
            int chunk = col4 >> 1;
            int idx = row * 256 + ((chunk ^ (row & 7)) * 8) + (col4 & 1) * 4;
            uint2 wv;
            wv.x = __builtin_bit_cast(unsigned, h0);
            wv.y = __builtin_bit_cast(unsigned, h1);
            *(uint2*)(Bs + idx) = wv;
        }
        barrier_lgkm();

        float acc[4][4];
#pragma unroll
        for (int jm = 0; jm < 4; ++jm)
#pragma unroll
            for (int jn = 0; jn < 4; ++jn) acc[jm][jn] = 0.f;

#pragma unroll 4
        for (int kc = 0; kc < 32; ++kc) {
            union { uint4 u; half2_t h[4]; } av[4], bv[4];
#pragma unroll
            for (int jm = 0; jm < 4; ++jm) {
                int r = ty * 4 + jm;
                av[jm].u = *(const uint4*)(As + r * 256 + ((kc ^ (r & 7)) * 8));
            }
#pragma unroll
            for (int jn = 0; jn < 4; ++jn) {
                int r = tx + 16 * jn;
                bv[jn].u = *(const uint4*)(Bs + r * 256 + ((kc ^ (r & 7)) * 8));
            }
#pragma unroll
            for (int jm = 0; jm < 4; ++jm)
#pragma unroll
                for (int jn = 0; jn < 4; ++jn)
#pragma unroll
                    for (int p = 0; p < 4; ++p)
                        acc[jm][jn] = fdot2(av[jm].h[p], bv[jn].h[p], acc[jm][jn]);
        }

#pragma unroll
        for (int jn = 0; jn < 4; ++jn) {
            int n = nb * 64 + tx + 16 * jn;
            float bias = bih[n] + (n < 512 ? bhh[n] : 0.f);
#pragma unroll
            for (int jm = 0; jm < 4; ++jm) {
                int m = m0 + ty * 4 + jm;
                gx[(size_t)m * G3 + n] = (_Float16)(acc[jm][jn] + bias);
            }
        }
        barrier_lgkm();   // WAR: Bs restage next iteration
    }
}

// ---------------------------------------------------------------------------
// Kernel 2: recurrence. grid=64 (b,dir), block=768 (12 waves).
// Wave w: k-segment s=w&3 (64 k), row-group g=w>>2 (256 rows).
// Lane: 4 rows x 64 k of W_hh = 128 packed fp16 regs.
// Bias bookkeeping: b_ih (all) + b_hh (r,z rows) live in gx; b_hn (rows
// 512..767) is folded into the dot partials by the s==0, g==2 wave so the
// gate's r*hn multiply sees it inside hn. 2 lgkm-only barriers/step.
// ---------------------------------------------------------------------------
__attribute__((amdgpu_waves_per_eu(1, 3)))
__global__ __launch_bounds__(768) void gru_seq(
        const _Float16* __restrict__ gx,
        const float* __restrict__ Whh,
        const float* __restrict__ bhh,
        float* __restrict__ out0,     // outputs [32,2048,512]
        float* __restrict__ out1) {   // hiddens [2048,32,512]
    __shared__ float  P[4 * 768];     // 12KB partials
    __shared__ ushort h16[256];       // h as fp16
    __shared__ ushort gxb[768];       // this step's gx row (fp16)

    const int tid = threadIdx.x;
    const int b   = blockIdx.x & 31;
    const int d   = blockIdx.x >> 5;
    const int w   = tid >> 6;
    const int L   = tid & 63;
    const int s   = w & 3;            // k segment
    const int g   = w >> 2;           // row group (0..2)

    // ---- W_hh fragment -> registers as packed fp16 ----
    // Wb folds ONLY b_hn (rows 512..767): r,z biases are already in gx.
    half2_t Wr[4][32];
    float   Wb[4];
#pragma unroll
    for (int jr = 0; jr < 4; ++jr) {
        const int row = g * 256 + jr * 64 + L;
        const float* wrow = Whh + (size_t)row * HID + s * 64;
#pragma unroll
        for (int q = 0; q < 32; ++q) {
            float2 wv = *(const float2*)(wrow + 2 * q);
            Wr[jr][q] = __builtin_amdgcn_cvt_pkrtz(wv.x, wv.y);
        }
        Wb[jr] = (s == 0 && row >= 512) ? bhh[row] : 0.f;
    }

    float hprev = 0.f;
    if (tid < 256) h16[tid] = 0;      // h0 = 0

    const int tp0 = d ? (T_STEPS - 1) : 0;
    const int sgn = d ? -1 : 1;

    const _Float16* gp = gx + ((size_t)b * T_STEPS + tp0) * G3 + tid * 8;
    const int gpd = sgn * G3;
    uint4 greg{};
    if (tid < 96) greg = *(const uint4*)gp;

    float* o0 = out0 + ((size_t)b * T_STEPS + tp0) * 512 + d * 256 + tid;
    float* o1 = out1 + ((size_t)tp0 * BATCH + b) * 512 + d * 256 + tid;
    const int o0d = sgn * 512;
    const int o1d = sgn * (BATCH * 512);

    __syncthreads();

    for (int t = 0; t < T_STEPS; ++t) {
        // land this step's gx row in LDS; issue next step's load (hides HBM
        // latency under dot+gate; lgkm-only barriers keep it in flight)
        if (tid < 96) {
            *(uint4*)(gxb + tid * 8) = greg;
            if (t + 1 < T_STEPS) {
                gp += gpd;
                greg = *(const uint4*)gp;
            }
        }

        // ---- dot phase: 128 fdot2 per lane ----
        float acc[4] = {Wb[0], Wb[1], Wb[2], Wb[3]};
#pragma unroll
        for (int c = 0; c < 4; ++c) {
            union { uint4 u; half2_t h[4]; } hh0, hh1;
            hh0.u = *(const uint4*)(h16 + s * 64 + c * 16);       // broadcast
            hh1.u = *(const uint4*)(h16 + s * 64 + c * 16 + 8);   // broadcast
#pragma unroll
            for (int jr = 0; jr < 4; ++jr) {
#pragma unroll
                for (int p = 0; p < 4; ++p) {
                    acc[jr] = fdot2(Wr[jr][c * 8 + p],     hh0.h[p], acc[jr]);
                    acc[jr] = fdot2(Wr[jr][c * 8 + 4 + p], hh1.h[p], acc[jr]);
                }
            }
        }
#pragma unroll
        for (int jr = 0; jr < 4; ++jr)
            P[s * 768 + g * 256 + jr * 64 + L] = acc[jr];

        barrier_lgkm();

        // ---- gate phase (first 4 waves) ----
        if (tid < 256) {
            const int i = tid;
            float hr = (P[i]       + P[768 + i])  + (P[1536 + i] + P[2304 + i]);
            float hz = (P[256 + i] + P[1024 + i]) + (P[1792 + i] + P[2560 + i]);
            float hn = (P[512 + i] + P[1280 + i]) + (P[2048 + i] + P[2816 + i]);
            const _Float16* gxh = (const _Float16*)gxb;
            float xr = (float)gxh[i]       + hr;   // b_ih+b_hr in gx
            float xz = (float)gxh[256 + i] + hz;   // b_ih+b_hz in gx
            // sigmoid via exp2; saturates cleanly at +-inf (no NaN)
            float r = __builtin_amdgcn_rcpf(1.f + __builtin_amdgcn_exp2f(xr * -1.44269504f));
            float z = __builtin_amdgcn_rcpf(1.f + __builtin_amdgcn_exp2f(xz * -1.44269504f));
            float nx = (float)gxh[512 + i] + r * hn;   // hn includes b_hn
            float e2 = __builtin_amdgcn_exp2f(nx * 2.88539008f);
            float n  = 1.f - 2.f * __builtin_amdgcn_rcpf(1.f + e2);   // tanh
            float h  = n + z * (hprev - n);
            hprev = h;

            h16[i] = __builtin_bit_cast(ushort, (_Float16)h);
            *o0 = h; *o1 = h;
            o0 += o0d; o1 += o1d;
        }
        barrier_lgkm();
    }
}

// ---------------------------------------------------------------------------
extern "C" void kernel_launch(void* const* d_in, const int* in_sizes, int n_in,
                              void* d_out, int out_size, void* d_ws, size_t ws_size,
                              hipStream_t stream) {
    const float* x   = (const float*)d_in[0];
    const float* Wih = (const float*)d_in[1];
    const float* Whh = (const float*)d_in[2];
    const float* bih = (const float*)d_in[3];
    const float* bhh = (const float*)d_in[4];

    float* out0 = (float*)d_out;                          // outputs [32,2048,512]
    float* out1 = out0 + (size_t)BATCH * T_STEPS * 512;   // hiddens [2048,32,512]

    _Float16* gx = (_Float16*)d_ws;                       // 96MB

    gx_gemm<<<dim3(65536 / 64), dim3(256), 0, stream>>>(x, Wih, bih, bhh, gx);
    gru_seq<<<dim3(BATCH * 2), dim3(768), 0, stream>>>(gx, Whh, bhh, out0, out1);
}